// Round 6
// baseline (937.657 us; speedup 1.0000x reference)
//
#include <hip/hip_runtime.h>
#include <cstdint>
#include <cstddef>

#define BB 64
#define TT 512
#define II 256
#define HH 256
#define GG 768   // 3*H

typedef _Float16 f16x2 __attribute__((ext_vector_type(2)));
typedef _Float16 f16x8 __attribute__((ext_vector_type(8)));
typedef float    f32x4 __attribute__((ext_vector_type(4)));

__device__ __forceinline__ float sigf(float x)       { return 1.f / (1.f + __expf(-x)); }
__device__ __forceinline__ float tanh_fast(float x)  { return 1.f - 2.f / (__expf(2.f * x) + 1.f); }

__device__ __forceinline__ float dot2(uint32_t w, uint32_t h, float acc) {
#if defined(__has_builtin)
#if __has_builtin(__builtin_amdgcn_fdot2)
    return __builtin_amdgcn_fdot2(__builtin_bit_cast(f16x2, w),
                                  __builtin_bit_cast(f16x2, h), acc, false);
#else
    f16x2 a = __builtin_bit_cast(f16x2, w), b = __builtin_bit_cast(f16x2, h);
    return acc + (float)a.x * (float)b.x + (float)a.y * (float)b.y;
#endif
#else
    f16x2 a = __builtin_bit_cast(f16x2, w), b = __builtin_bit_cast(f16x2, h);
    return acc + (float)a.x * (float)b.x + (float)a.y * (float)b.y;
#endif
}

__device__ __forceinline__ uint32_t packf16(float a, float b) {
    f16x2 v; v.x = (_Float16)a; v.y = (_Float16)b;
    return __builtin_bit_cast(uint32_t, v);
}

// quad_perm add: acc += value from quad lane permutation (explicit indices)
template <int CTRL>
__device__ __forceinline__ float qadd(float v) {
    int y = __builtin_amdgcn_update_dpp(0, __builtin_bit_cast(int, v),
                                        CTRL, 0xf, 0xf, true);
    return v + __builtin_bit_cast(float, y);
}

// ---------------------------------------------------------------------------
// Kernel A: pack Wh for the 256-thread k-split scan.
// Scan thread t (0..255): chunk c = t&3 (k in [c*64,(c+1)*64)), rows
// r(t,j) = j*64 + (t>>2), j = 0..11.  wf[j*32+m] = f16x2(Wh[r][c*64+2m], +1).
// Global layout: wpk[d][jm*256 + t], jm = j*32+m in [0,384).
// ---------------------------------------------------------------------------
__global__ void pack_wh(const float* __restrict__ Whf,
                        const float* __restrict__ Whb,
                        uint32_t* __restrict__ wpk)
{
    int idx = blockIdx.x * 256 + threadIdx.x;   // 0 .. 196607
    int d = idx >= 98304;
    int u = idx - d * 98304;                    // 0 .. 98303
    int t  = u & 255;
    int jm = u >> 8;                            // 0 .. 383
    int j = jm >> 5, m = jm & 31;
    int r = j * 64 + (t >> 2);
    int c = t & 3;
    const float* __restrict__ W = d ? Whb : Whf;
    const float* base = &W[(size_t)r * II + c * 64 + 2 * m];
    wpk[(size_t)d * 98304 + (size_t)jm * 256 + t] = packf16(base[0], base[1]);
}

// ---------------------------------------------------------------------------
// Kernel B: MFMA f16 GEMM for gi (unchanged from R5).
// ---------------------------------------------------------------------------
__global__ __launch_bounds__(256) void gi_gemm_mfma(
    const float* __restrict__ x,
    const float* __restrict__ Wif, const float* __restrict__ bif,
    const float* __restrict__ Wib, const float* __restrict__ bib,
    float* __restrict__ gi)
{
    __shared__ __align__(16) _Float16 Asm[8][64][8];   // 8 KB
    __shared__ __align__(16) _Float16 Bsm[8][64][8];   // 8 KB

    const int ntile = blockIdx.x % 12;
    const int mtile = blockIdx.x / 12;
    const int m0 = mtile * 64;
    const int n0 = ntile * 64;
    const int d  = m0 >> 15;
    const int xrow0 = m0 & 32767;
    const float* __restrict__ W    = d ? Wib : Wif;
    const float* __restrict__ bias = d ? bib : bif;

    const int tid  = threadIdx.x;
    const int w    = tid >> 6;
    const int lane = tid & 63;
    const int lr   = lane & 15;
    const int lk8  = (lane >> 4);

    f32x4 acc[4] = {};

    const int srow = tid >> 2;
    const int scol = (tid & 3) * 16;

    for (int k0 = 0; k0 < II; k0 += 64) {
        const float* ap = &x[(size_t)(xrow0 + srow) * II + k0 + scol];
        const float* bp = &W[(size_t)(n0 + srow)   * II + k0 + scol];
#pragma unroll
        for (int half = 0; half < 2; ++half) {
            float4 a0 = *(const float4*)(ap + 8 * half);
            float4 a1 = *(const float4*)(ap + 8 * half + 4);
            float4 b0 = *(const float4*)(bp + 8 * half);
            float4 b1 = *(const float4*)(bp + 8 * half + 4);
            f16x8 av, bv;
            av[0] = (_Float16)a0.x; av[1] = (_Float16)a0.y;
            av[2] = (_Float16)a0.z; av[3] = (_Float16)a0.w;
            av[4] = (_Float16)a1.x; av[5] = (_Float16)a1.y;
            av[6] = (_Float16)a1.z; av[7] = (_Float16)a1.w;
            bv[0] = (_Float16)b0.x; bv[1] = (_Float16)b0.y;
            bv[2] = (_Float16)b0.z; bv[3] = (_Float16)b0.w;
            bv[4] = (_Float16)b1.x; bv[5] = (_Float16)b1.y;
            bv[6] = (_Float16)b1.z; bv[7] = (_Float16)b1.w;
            *(f16x8*)&Asm[scol / 8 + half][srow][0] = av;
            *(f16x8*)&Bsm[scol / 8 + half][srow][0] = bv;
        }
        __syncthreads();

#pragma unroll
        for (int kk = 0; kk < 2; ++kk) {
            const int kb = kk * 4 + lk8;
            f16x8 af = *(const f16x8*)&Asm[kb][16 * w + lr][0];
#pragma unroll
            for (int j = 0; j < 4; ++j) {
                f16x8 bf = *(const f16x8*)&Bsm[kb][16 * j + lr][0];
                acc[j] = __builtin_amdgcn_mfma_f32_16x16x32_f16(af, bf, acc[j], 0, 0, 0);
            }
        }
        __syncthreads();
    }

    const int rbase = m0 + 16 * w + (lane >> 4) * 4;
#pragma unroll
    for (int j = 0; j < 4; ++j) {
        const int col = n0 + 16 * j + lr;
        const float bcol = bias[col];
#pragma unroll
        for (int r = 0; r < 4; ++r) {
            gi[(size_t)(rbase + r) * GG + col] = acc[j][r] + bcol;
        }
    }
}

// ---------------------------------------------------------------------------
// Kernel C: 256-thread scan, 1 wave/SIMD (VGPR cap 512).
// Thread t: chunk c=t&3, rows {j*64+(t>>2)} j=0..11 -> 384 f16x2 weight regs.
// Per step: 8 ds_read_b128 (its h chunk, broadcast), 384 dot2, quad DPP
// butterfly reduce (no partials in LDS), in-register gate math for output
// o = 64*(t&3) + (t>>2), h_prev register-resident, gi prefetched to regs.
// ONE barrier per step (hpk double-buffered; all hazard pairs span it).
// ---------------------------------------------------------------------------
__global__ __launch_bounds__(256, 1) void gru_scan_reg4(
    const float* __restrict__ gi,     // [2][B][T][G] fp32
    const uint32_t* __restrict__ wpk,
    const float* __restrict__ h0f, const float* __restrict__ h0b,
    const float* __restrict__ bhf, const float* __restrict__ bhb,
    float* __restrict__ out)
{
    __shared__ __align__(16) uint32_t hpk[2][4 * 36];  // 4 chunks, 32 u32 + 4 pad

    const int bx = blockIdx.x;
    const int d  = bx >> 6;
    const int b  = bx & 63;
    const int t  = threadIdx.x;       // 0..255
    const int a  = t >> 2;            // 0..63
    const int q  = t & 3;             // quad slot == k-chunk c
    const int o  = 64 * q + a;        // owned output index 0..255

    const float* __restrict__ bh = d ? bhb : bhf;
    const float* __restrict__ h0 = d ? h0b : h0f;

    // ---- weights into registers (coalesced; one-time) ----
    const uint32_t* __restrict__ wp = wpk + (size_t)d * 98304;
    uint32_t wf[384];
#pragma unroll
    for (int jm = 0; jm < 384; ++jm) wf[jm] = wp[(size_t)jm * 256 + t];

    // ---- h0: register h_prev + packed f16x2 into hpk[0] ----
    float hp = h0[(size_t)b * HH + o];
    {
        float hb4 = __shfl_down(hp, 4);       // value of output o+1 (even a)
        if (!(a & 1)) {
            int m = o >> 1;                   // 32q + (a>>1)
            hpk[0][(m >> 5) * 36 + (m & 31)] = packf16(hp, hb4);
        }
    }

    const float bhr = bh[o];
    const float bhz = bh[HH + o];
    const float bhn = bh[2 * HH + o];

    const int dir = d ? -1 : 1;
    int ta = d ? (TT - 1) : 0;
    const float* __restrict__ gp =
        gi + ((size_t)d * BB + b) * (size_t)TT * GG + (size_t)ta * GG;
    float g0 = gp[o], g1 = gp[HH + o], g2 = gp[2 * HH + o];

    __syncthreads();

    for (int s = 0; s < TT; ++s) {
        const int cur = s & 1;

        const float ir = g0, iz = g1, inn = g2;
        if (s + 1 < TT) {
            gp += (ptrdiff_t)dir * GG;
            g0 = gp[o]; g1 = gp[HH + o]; g2 = gp[2 * HH + o];
        }

        // ---- dot phase: 8 uint4 broadcast reads, 384 dot2 into 12 accs ----
        const uint32_t* __restrict__ hb = &hpk[cur][q * 36];
        float acc[12] = {};
#pragma unroll
        for (int q8 = 0; q8 < 8; ++q8) {
            uint4 h4 = *(const uint4*)&hb[q8 * 4];
#pragma unroll
            for (int j = 0; j < 12; ++j) {
                acc[j] = dot2(wf[j * 32 + q8 * 4 + 0], h4.x, acc[j]);
                acc[j] = dot2(wf[j * 32 + q8 * 4 + 1], h4.y, acc[j]);
                acc[j] = dot2(wf[j * 32 + q8 * 4 + 2], h4.z, acc[j]);
                acc[j] = dot2(wf[j * 32 + q8 * 4 + 3], h4.w, acc[j]);
            }
        }

        // ---- quad butterfly: all 4 lanes get full row sums (no LDS) ----
#pragma unroll
        for (int j = 0; j < 12; ++j) {
            acc[j] = qadd<0xB1>(acc[j]);   // quad_perm [1,0,3,2]  (xor 1)
            acc[j] = qadd<0x4E>(acc[j]);   // quad_perm [2,3,0,1]  (xor 2)
        }

        // rows for output o: r-gate row o (j=q), z row 256+o (j=4+q), n row 512+o (j=8+q)
        float hr = q < 2 ? (q == 0 ? acc[0] : acc[1]) : (q == 2 ? acc[2] : acc[3]);
        float hz = q < 2 ? (q == 0 ? acc[4] : acc[5]) : (q == 2 ? acc[6] : acc[7]);
        float hn = q < 2 ? (q == 0 ? acc[8] : acc[9]) : (q == 2 ? acc[10] : acc[11]);
        hr += bhr; hz += bhz; hn += bhn;

        float r = sigf(ir + hr);
        float z = sigf(iz + hz);
        float n = tanh_fast(inn + r * hn);
        float hnew = tanh_fast((1.f - z) * n + z * hp);
        hp = hnew;
        out[((size_t)b * TT + ta) * (2 * HH) + d * HH + o] = hnew;

        float hb4 = __shfl_down(hnew, 4);     // output o+1's value (even a)
        if (!(a & 1)) {
            int m = o >> 1;
            hpk[cur ^ 1][(m >> 5) * 36 + (m & 31)] = packf16(hnew, hb4);
        }
        ta += dir;
        __syncthreads();
    }
}

// ---------------------------------------------------------------------------
// Fallback scan (ws too small): unchanged known-good path.
// ---------------------------------------------------------------------------
__global__ __launch_bounds__(768) void gru_scan_fallback(
    const float* __restrict__ x,
    const float* __restrict__ h0f, const float* __restrict__ h0b,
    const float* __restrict__ Wif, const float* __restrict__ bif_,
    const float* __restrict__ Whf, const float* __restrict__ bhf,
    const float* __restrict__ Wib, const float* __restrict__ bib_,
    const float* __restrict__ Whb, const float* __restrict__ bhb,
    float* __restrict__ out)
{
    __shared__ __align__(16) float hbuf[2][HH];
    __shared__ float gh_s[GG];
    __shared__ float gi_s[GG];
    __shared__ __align__(16) float xrow[II];

    const int bx  = blockIdx.x;
    const int d   = bx >> 6;
    const int b   = bx & 63;
    const int tid = threadIdx.x;

    const float* __restrict__ Wh = d ? Whb : Whf;
    const float* __restrict__ bh = d ? bhb : bhf;
    const float* __restrict__ Wi = d ? Wib : Wif;
    const float* __restrict__ bi = d ? bib_ : bif_;
    const float* __restrict__ h0 = d ? h0b : h0f;

    if (tid < HH) hbuf[0][tid] = h0[(size_t)b * HH + tid];

    const float bh_row = bh[tid];
    const float bi_row = bi[tid];
    const float4* __restrict__ whr = (const float4*)(Wh + (size_t)tid * II);
    const float4* __restrict__ wir = (const float4*)(Wi + (size_t)tid * II);

    __syncthreads();

    for (int s = 0; s < TT; ++s) {
        const int ta  = d ? (TT - 1 - s) : s;
        const int cur = s & 1;

        if (tid < II) xrow[tid] = x[((size_t)b * TT + ta) * II + tid];
        __syncthreads();

        const float4* hv4 = (const float4*)hbuf[cur];
        float a0 = 0.f, a1 = 0.f, a2 = 0.f, a3 = 0.f;
#pragma unroll 4
        for (int k = 0; k < II / 4; k += 4) {
            float4 w0 = whr[k], w1 = whr[k + 1], w2 = whr[k + 2], w3 = whr[k + 3];
            float4 q0 = hv4[k], q1 = hv4[k + 1], q2 = hv4[k + 2], q3 = hv4[k + 3];
            a0 += w0.x * q0.x + w0.y * q0.y + w0.z * q0.z + w0.w * q0.w;
            a1 += w1.x * q1.x + w1.y * q1.y + w1.z * q1.z + w1.w * q1.w;
            a2 += w2.x * q2.x + w2.y * q2.y + w2.z * q2.z + w2.w * q2.w;
            a3 += w3.x * q3.x + w3.y * q3.y + w3.z * q3.z + w3.w * q3.w;
        }
        gh_s[tid] = (a0 + a1) + (a2 + a3) + bh_row;

        const float4* xv4 = (const float4*)xrow;
        float c0 = 0.f, c1 = 0.f, c2 = 0.f, c3 = 0.f;
#pragma unroll 4
        for (int k = 0; k < II / 4; k += 4) {
            float4 w0 = wir[k], w1 = wir[k + 1], w2 = wir[k + 2], w3 = wir[k + 3];
            float4 q0 = xv4[k], q1 = xv4[k + 1], q2 = xv4[k + 2], q3 = xv4[k + 3];
            c0 += w0.x * q0.x + w0.y * q0.y + w0.z * q0.z + w0.w * q0.w;
            c1 += w1.x * q1.x + w1.y * q1.y + w1.z * q1.z + w1.w * q1.w;
            c2 += w2.x * q2.x + w2.y * q2.y + w2.z * q2.z + w2.w * q2.w;
            c3 += w3.x * q3.x + w3.y * q3.y + w3.z * q3.z + w3.w * q3.w;
        }
        gi_s[tid] = (c0 + c1) + (c2 + c3) + bi_row;
        __syncthreads();

        if (tid < HH) {
            float ir = gi_s[tid], iz = gi_s[HH + tid], inn = gi_s[2 * HH + tid];
            float hr = gh_s[tid], hz = gh_s[HH + tid], hn = gh_s[2 * HH + tid];
            float r  = sigf(ir + hr);
            float z  = sigf(iz + hz);
            float n  = tanh_fast(inn + r * hn);
            float hp = hbuf[cur][tid];
            float hnew = tanh_fast((1.f - z) * n + z * hp);
            hbuf[cur ^ 1][tid] = hnew;
            out[((size_t)b * TT + ta) * (2 * HH) + d * HH + tid] = hnew;
        }
        __syncthreads();
    }
}

// ---------------------------------------------------------------------------
extern "C" void kernel_launch(void* const* d_in, const int* in_sizes, int n_in,
                              void* d_out, int out_size, void* d_ws, size_t ws_size,
                              hipStream_t stream)
{
    const float* x   = (const float*)d_in[0];
    const float* h0f = (const float*)d_in[1];
    const float* h0b = (const float*)d_in[2];
    const float* Wif = (const float*)d_in[3];
    const float* Whf = (const float*)d_in[4];
    const float* bif = (const float*)d_in[5];
    const float* bhf = (const float*)d_in[6];
    const float* Wib = (const float*)d_in[7];
    const float* Whb = (const float*)d_in[8];
    const float* bib = (const float*)d_in[9];
    const float* bhb = (const float*)d_in[10];
    float* out = (float*)d_out;

    const size_t gi_bytes  = (size_t)2 * BB * TT * GG * sizeof(float);  // 201,326,592
    const size_t wpk_bytes = (size_t)2 * 98304 * sizeof(uint32_t);      //     786,432

    if (ws_size >= gi_bytes + wpk_bytes) {
        float*    gi  = (float*)d_ws;
        uint32_t* wpk = (uint32_t*)((char*)d_ws + gi_bytes);

        pack_wh<<<768, 256, 0, stream>>>(Whf, Whb, wpk);

        gi_gemm_mfma<<<12288, 256, 0, stream>>>(x, Wif, bif, Wib, bib, gi);

        gru_scan_reg4<<<128, 256, 0, stream>>>(gi, wpk, h0f, h0b, bhf, bhb, out);
    } else {
        gru_scan_fallback<<<128, 768, 0, stream>>>(
            x, h0f, h0b, Wif, bif, Whf, bhf, Wib, bib, Whb, bhb, out);
    }
}

// Round 7
// 737.776 us; speedup vs baseline: 1.2709x; 1.2709x over previous
//
#include <hip/hip_runtime.h>
#include <cstdint>
#include <cstddef>

#define BB 64
#define TT 512
#define II 256
#define HH 256
#define GG 768   // 3*H

typedef _Float16 f16x2 __attribute__((ext_vector_type(2)));
typedef _Float16 f16x8 __attribute__((ext_vector_type(8)));
typedef float    f32x4 __attribute__((ext_vector_type(4)));

__device__ __forceinline__ float sigf(float x)       { return 1.f / (1.f + __expf(-x)); }
__device__ __forceinline__ float tanh_fast(float x)  { return 1.f - 2.f / (__expf(2.f * x) + 1.f); }

__device__ __forceinline__ float dot2(uint32_t w, uint32_t h, float acc) {
#if defined(__has_builtin)
#if __has_builtin(__builtin_amdgcn_fdot2)
    return __builtin_amdgcn_fdot2(__builtin_bit_cast(f16x2, w),
                                  __builtin_bit_cast(f16x2, h), acc, false);
#else
    f16x2 a = __builtin_bit_cast(f16x2, w), b = __builtin_bit_cast(f16x2, h);
    return acc + (float)a.x * (float)b.x + (float)a.y * (float)b.y;
#endif
#else
    f16x2 a = __builtin_bit_cast(f16x2, w), b = __builtin_bit_cast(f16x2, h);
    return acc + (float)a.x * (float)b.x + (float)a.y * (float)b.y;
#endif
}

__device__ __forceinline__ uint32_t packf16(float a, float b) {
    f16x2 v; v.x = (_Float16)a; v.y = (_Float16)b;
    return __builtin_bit_cast(uint32_t, v);
}

// quad_perm add: acc += value from quad lane permutation (explicit indices)
template <int CTRL>
__device__ __forceinline__ float qadd(float v) {
    int y = __builtin_amdgcn_update_dpp(0, __builtin_bit_cast(int, v),
                                        CTRL, 0xf, 0xf, true);
    return v + __builtin_bit_cast(float, y);
}

// ---------------------------------------------------------------------------
// Kernel A: pack Wh for the 512-thread k-split scan (R4 layout).
// Scan thread t (0..511): chunk c = t&3 (k in [c*64,(c+1)*64)), rows
// r(t,j) = j*128 + (t>>2), j = 0..5.  wf[j*32+m] = f16x2(Wh[r][c*64+2m], +1).
// Global layout: wpk[d][jm*512 + t], jm = j*32+m in [0,192).
// ---------------------------------------------------------------------------
__global__ void pack_wh(const float* __restrict__ Whf,
                        const float* __restrict__ Whb,
                        uint32_t* __restrict__ wpk)
{
    int idx = blockIdx.x * 256 + threadIdx.x;   // 0 .. 196607
    int d = idx >= 98304;
    int u = idx - d * 98304;                    // 0 .. 98303
    int t  = u & 511;
    int jm = u >> 9;                            // 0 .. 191
    int j = jm >> 5, m = jm & 31;
    int r = j * 128 + (t >> 2);
    int c = t & 3;
    const float* __restrict__ W = d ? Whb : Whf;
    const float* base = &W[(size_t)r * II + c * 64 + 2 * m];
    wpk[(size_t)d * 98304 + (size_t)jm * 512 + t] = packf16(base[0], base[1]);
}

// ---------------------------------------------------------------------------
// Kernel B: MFMA f16 GEMM for gi (unchanged from R5).
// ---------------------------------------------------------------------------
__global__ __launch_bounds__(256) void gi_gemm_mfma(
    const float* __restrict__ x,
    const float* __restrict__ Wif, const float* __restrict__ bif,
    const float* __restrict__ Wib, const float* __restrict__ bib,
    float* __restrict__ gi)
{
    __shared__ __align__(16) _Float16 Asm[8][64][8];   // 8 KB
    __shared__ __align__(16) _Float16 Bsm[8][64][8];   // 8 KB

    const int ntile = blockIdx.x % 12;
    const int mtile = blockIdx.x / 12;
    const int m0 = mtile * 64;
    const int n0 = ntile * 64;
    const int d  = m0 >> 15;
    const int xrow0 = m0 & 32767;
    const float* __restrict__ W    = d ? Wib : Wif;
    const float* __restrict__ bias = d ? bib : bif;

    const int tid  = threadIdx.x;
    const int w    = tid >> 6;
    const int lane = tid & 63;
    const int lr   = lane & 15;
    const int lk8  = (lane >> 4);

    f32x4 acc[4] = {};

    const int srow = tid >> 2;
    const int scol = (tid & 3) * 16;

    for (int k0 = 0; k0 < II; k0 += 64) {
        const float* ap = &x[(size_t)(xrow0 + srow) * II + k0 + scol];
        const float* bp = &W[(size_t)(n0 + srow)   * II + k0 + scol];
#pragma unroll
        for (int half = 0; half < 2; ++half) {
            float4 a0 = *(const float4*)(ap + 8 * half);
            float4 a1 = *(const float4*)(ap + 8 * half + 4);
            float4 b0 = *(const float4*)(bp + 8 * half);
            float4 b1 = *(const float4*)(bp + 8 * half + 4);
            f16x8 av, bv;
            av[0] = (_Float16)a0.x; av[1] = (_Float16)a0.y;
            av[2] = (_Float16)a0.z; av[3] = (_Float16)a0.w;
            av[4] = (_Float16)a1.x; av[5] = (_Float16)a1.y;
            av[6] = (_Float16)a1.z; av[7] = (_Float16)a1.w;
            bv[0] = (_Float16)b0.x; bv[1] = (_Float16)b0.y;
            bv[2] = (_Float16)b0.z; bv[3] = (_Float16)b0.w;
            bv[4] = (_Float16)b1.x; bv[5] = (_Float16)b1.y;
            bv[6] = (_Float16)b1.z; bv[7] = (_Float16)b1.w;
            *(f16x8*)&Asm[scol / 8 + half][srow][0] = av;
            *(f16x8*)&Bsm[scol / 8 + half][srow][0] = bv;
        }
        __syncthreads();

#pragma unroll
        for (int kk = 0; kk < 2; ++kk) {
            const int kb = kk * 4 + lk8;
            f16x8 af = *(const f16x8*)&Asm[kb][16 * w + lr][0];
#pragma unroll
            for (int j = 0; j < 4; ++j) {
                f16x8 bf = *(const f16x8*)&Bsm[kb][16 * j + lr][0];
                acc[j] = __builtin_amdgcn_mfma_f32_16x16x32_f16(af, bf, acc[j], 0, 0, 0);
            }
        }
        __syncthreads();
    }

    const int rbase = m0 + 16 * w + (lane >> 4) * 4;
#pragma unroll
    for (int j = 0; j < 4; ++j) {
        const int col = n0 + 16 * j + lr;
        const float bcol = bias[col];
#pragma unroll
        for (int r = 0; r < 4; ++r) {
            gi[(size_t)(rbase + r) * GG + col] = acc[j][r] + bcol;
        }
    }
}

// ---------------------------------------------------------------------------
// Kernel C: 512-thread scan (2 waves/SIMD) + quad-DPP butterfly reduction.
// Thread t: a=t>>2 (0..127), q=t&3; chunk c=q, rows {j*128+a} j=0..5.
// Quad 4a holds all 4 k-chunks of the same 6 rows -> 2-stage quad_perm
// butterfly gives every lane full row sums in-register: no part[] LDS,
// no gis[] LDS, h_prev in register.  Lanes q<2 own output a, q>=2 own
// output 128+a (acc[0,2,4] vs acc[1,3,5] = r/z/n rows).
// ONE barrier per step (hpk double-buffered; all hazard pairs span it).
// ---------------------------------------------------------------------------
__global__ __launch_bounds__(512, 2) void gru_scan_reg5(
    const float* __restrict__ gi,     // [2][B][T][G] fp32
    const uint32_t* __restrict__ wpk,
    const float* __restrict__ h0f, const float* __restrict__ h0b,
    const float* __restrict__ bhf, const float* __restrict__ bhb,
    float* __restrict__ out)
{
    __shared__ __align__(16) uint32_t hpk[2][4 * 36];  // 4 chunks, 32 u32 + 4 pad

    const int bx = blockIdx.x;
    const int d  = bx >> 6;
    const int b  = bx & 63;
    const int t  = threadIdx.x;       // 0..511
    const int a  = t >> 2;            // 0..127
    const int q  = t & 3;             // quad slot == k-chunk c
    const int o  = (q < 2) ? a : (128 + a);   // owned output index

    const float* __restrict__ bh = d ? bhb : bhf;
    const float* __restrict__ h0 = d ? h0b : h0f;

    // ---- weights into registers (coalesced; one-time) ----
    const uint32_t* __restrict__ wp = wpk + (size_t)d * 98304;
    uint32_t wf[192];
#pragma unroll
    for (int jm = 0; jm < 192; ++jm) wf[jm] = wp[(size_t)jm * 512 + t];

    // ---- h0: register h_prev + packed f16x2 into hpk[0] ----
    float hp = h0[(size_t)b * HH + o];
    {
        float hnb = __shfl_down(hp, 4);       // output o+1's value (even a)
        if (!(a & 1) && !(q & 1)) {           // q==0 (m=a/2) or q==2 (m=64+a/2)
            int m = (q == 0) ? (a >> 1) : (64 + (a >> 1));
            hpk[0][(m >> 5) * 36 + (m & 31)] = packf16(hp, hnb);
        }
    }

    const float bhr = bh[o];
    const float bhz = bh[HH + o];
    const float bhn = bh[2 * HH + o];

    const int dir = d ? -1 : 1;
    int ta = d ? (TT - 1) : 0;
    const float* __restrict__ gp =
        gi + ((size_t)d * BB + b) * (size_t)TT * GG + (size_t)ta * GG;
    float g0 = gp[o], g1 = gp[HH + o], g2 = gp[2 * HH + o];

    __syncthreads();

    for (int s = 0; s < TT; ++s) {
        const int cur = s & 1;

        const float ir = g0, iz = g1, inn = g2;
        if (s + 1 < TT) {
            gp += (ptrdiff_t)dir * GG;
            g0 = gp[o]; g1 = gp[HH + o]; g2 = gp[2 * HH + o];
        }

        // ---- dot phase: 8 uint4 broadcast reads, 192 dot2 into 6 accs ----
        const uint32_t* __restrict__ hb = &hpk[cur][q * 36];
        float acc[6] = {};
#pragma unroll
        for (int q8 = 0; q8 < 8; ++q8) {
            uint4 h4 = *(const uint4*)&hb[q8 * 4];
#pragma unroll
            for (int j = 0; j < 6; ++j) {
                acc[j] = dot2(wf[j * 32 + q8 * 4 + 0], h4.x, acc[j]);
                acc[j] = dot2(wf[j * 32 + q8 * 4 + 1], h4.y, acc[j]);
                acc[j] = dot2(wf[j * 32 + q8 * 4 + 2], h4.z, acc[j]);
                acc[j] = dot2(wf[j * 32 + q8 * 4 + 3], h4.w, acc[j]);
            }
        }

        // ---- quad butterfly: every lane gets full row sums (no LDS) ----
#pragma unroll
        for (int j = 0; j < 6; ++j) {
            acc[j] = qadd<0xB1>(acc[j]);   // quad_perm [1,0,3,2]  (xor 1)
            acc[j] = qadd<0x4E>(acc[j]);   // quad_perm [2,3,0,1]  (xor 2)
        }

        // acc[j] = full dot of row j*128+a.
        // output a   (q<2):  r=acc[0], z=acc[2], n=acc[4]
        // output 128+a (q>=2): r=acc[1], z=acc[3], n=acc[5]
        float hr = (q < 2) ? acc[0] : acc[1];
        float hz = (q < 2) ? acc[2] : acc[3];
        float hn = (q < 2) ? acc[4] : acc[5];
        hr += bhr; hz += bhz; hn += bhn;

        float r = sigf(ir + hr);
        float z = sigf(iz + hz);
        float n = tanh_fast(inn + r * hn);
        float hnew = tanh_fast((1.f - z) * n + z * hp);
        hp = hnew;
        if (!(q & 1))
            out[((size_t)b * TT + ta) * (2 * HH) + d * HH + o] = hnew;

        float hnb = __shfl_down(hnew, 4);     // output o+1's value (even a)
        if (!(a & 1) && !(q & 1)) {
            int m = (q == 0) ? (a >> 1) : (64 + (a >> 1));
            hpk[cur ^ 1][(m >> 5) * 36 + (m & 31)] = packf16(hnew, hnb);
        }
        ta += dir;
        __syncthreads();
    }
}

// ---------------------------------------------------------------------------
// Fallback scan (ws too small): unchanged known-good path.
// ---------------------------------------------------------------------------
__global__ __launch_bounds__(768) void gru_scan_fallback(
    const float* __restrict__ x,
    const float* __restrict__ h0f, const float* __restrict__ h0b,
    const float* __restrict__ Wif, const float* __restrict__ bif_,
    const float* __restrict__ Whf, const float* __restrict__ bhf,
    const float* __restrict__ Wib, const float* __restrict__ bib_,
    const float* __restrict__ Whb, const float* __restrict__ bhb,
    float* __restrict__ out)
{
    __shared__ __align__(16) float hbuf[2][HH];
    __shared__ float gh_s[GG];
    __shared__ float gi_s[GG];
    __shared__ __align__(16) float xrow[II];

    const int bx  = blockIdx.x;
    const int d   = bx >> 6;
    const int b   = bx & 63;
    const int tid = threadIdx.x;

    const float* __restrict__ Wh = d ? Whb : Whf;
    const float* __restrict__ bh = d ? bhb : bhf;
    const float* __restrict__ Wi = d ? Wib : Wif;
    const float* __restrict__ bi = d ? bib_ : bif_;
    const float* __restrict__ h0 = d ? h0b : h0f;

    if (tid < HH) hbuf[0][tid] = h0[(size_t)b * HH + tid];

    const float bh_row = bh[tid];
    const float bi_row = bi[tid];
    const float4* __restrict__ whr = (const float4*)(Wh + (size_t)tid * II);
    const float4* __restrict__ wir = (const float4*)(Wi + (size_t)tid * II);

    __syncthreads();

    for (int s = 0; s < TT; ++s) {
        const int ta  = d ? (TT - 1 - s) : s;
        const int cur = s & 1;

        if (tid < II) xrow[tid] = x[((size_t)b * TT + ta) * II + tid];
        __syncthreads();

        const float4* hv4 = (const float4*)hbuf[cur];
        float a0 = 0.f, a1 = 0.f, a2 = 0.f, a3 = 0.f;
#pragma unroll 4
        for (int k = 0; k < II / 4; k += 4) {
            float4 w0 = whr[k], w1 = whr[k + 1], w2 = whr[k + 2], w3 = whr[k + 3];
            float4 q0 = hv4[k], q1 = hv4[k + 1], q2 = hv4[k + 2], q3 = hv4[k + 3];
            a0 += w0.x * q0.x + w0.y * q0.y + w0.z * q0.z + w0.w * q0.w;
            a1 += w1.x * q1.x + w1.y * q1.y + w1.z * q1.z + w1.w * q1.w;
            a2 += w2.x * q2.x + w2.y * q2.y + w2.z * q2.z + w2.w * q2.w;
            a3 += w3.x * q3.x + w3.y * q3.y + w3.z * q3.z + w3.w * q3.w;
        }
        gh_s[tid] = (a0 + a1) + (a2 + a3) + bh_row;

        const float4* xv4 = (const float4*)xrow;
        float c0 = 0.f, c1 = 0.f, c2 = 0.f, c3 = 0.f;
#pragma unroll 4
        for (int k = 0; k < II / 4; k += 4) {
            float4 w0 = wir[k], w1 = wir[k + 1], w2 = wir[k + 2], w3 = wir[k + 3];
            float4 q0 = xv4[k], q1 = xv4[k + 1], q2 = xv4[k + 2], q3 = xv4[k + 3];
            c0 += w0.x * q0.x + w0.y * q0.y + w0.z * q0.z + w0.w * q0.w;
            c1 += w1.x * q1.x + w1.y * q1.y + w1.z * q1.z + w1.w * q1.w;
            c2 += w2.x * q2.x + w2.y * q2.y + w2.z * q2.z + w2.w * q2.w;
            c3 += w3.x * q3.x + w3.y * q3.y + w3.z * q3.z + w3.w * q3.w;
        }
        gi_s[tid] = (c0 + c1) + (c2 + c3) + bi_row;
        __syncthreads();

        if (tid < HH) {
            float ir = gi_s[tid], iz = gi_s[HH + tid], inn = gi_s[2 * HH + tid];
            float hr = gh_s[tid], hz = gh_s[HH + tid], hn = gh_s[2 * HH + tid];
            float r  = sigf(ir + hr);
            float z  = sigf(iz + hz);
            float n  = tanh_fast(inn + r * hn);
            float hp = hbuf[cur][tid];
            float hnew = tanh_fast((1.f - z) * n + z * hp);
            hbuf[cur ^ 1][tid] = hnew;
            out[((size_t)b * TT + ta) * (2 * HH) + d * HH + tid] = hnew;
        }
        __syncthreads();
    }
}

// ---------------------------------------------------------------------------
extern "C" void kernel_launch(void* const* d_in, const int* in_sizes, int n_in,
                              void* d_out, int out_size, void* d_ws, size_t ws_size,
                              hipStream_t stream)
{
    const float* x   = (const float*)d_in[0];
    const float* h0f = (const float*)d_in[1];
    const float* h0b = (const float*)d_in[2];
    const float* Wif = (const float*)d_in[3];
    const float* Whf = (const float*)d_in[4];
    const float* bif = (const float*)d_in[5];
    const float* bhf = (const float*)d_in[6];
    const float* Wib = (const float*)d_in[7];
    const float* Whb = (const float*)d_in[8];
    const float* bib = (const float*)d_in[9];
    const float* bhb = (const float*)d_in[10];
    float* out = (float*)d_out;

    const size_t gi_bytes  = (size_t)2 * BB * TT * GG * sizeof(float);  // 201,326,592
    const size_t wpk_bytes = (size_t)2 * 98304 * sizeof(uint32_t);      //     786,432

    if (ws_size >= gi_bytes + wpk_bytes) {
        float*    gi  = (float*)d_ws;
        uint32_t* wpk = (uint32_t*)((char*)d_ws + gi_bytes);

        pack_wh<<<768, 256, 0, stream>>>(Whf, Whb, wpk);

        gi_gemm_mfma<<<12288, 256, 0, stream>>>(x, Wif, bif, Wib, bib, gi);

        gru_scan_reg5<<<128, 512, 0, stream>>>(gi, wpk, h0f, h0b, bhf, bhb, out);
    } else {
        gru_scan_fallback<<<128, 768, 0, stream>>>(
            x, h0f, h0b, Wif, bif, Whf, bhf, Wib, bib, Whb, bhb, out);
    }
}